// Round 12
// baseline (415.111 us; speedup 1.0000x reference)
//
#include <hip/hip_runtime.h>
#include <hip/hip_bf16.h>
#include <stdint.h>

// ---------- types ----------
typedef __attribute__((ext_vector_type(8)))  short bf16x8;   // MFMA A/B frag (4 VGPR)
typedef __attribute__((ext_vector_type(16))) float f32x16;   // 32x32 MFMA C/D frag

__device__ __forceinline__ unsigned short f2bf(float f) {
  unsigned int u = __float_as_uint(f);
  u += 0x7FFFu + ((u >> 16) & 1u);   // round-to-nearest-even
  return (unsigned short)(u >> 16);
}

__device__ __forceinline__ void async_cp16(const void* g, void* l) {
  __builtin_amdgcn_global_load_lds((const __attribute__((address_space(1))) void*)g,
                                   (__attribute__((address_space(3))) void*)l,
                                   16, 0, 0);
}

// ---------- merged fp32 -> bf16 conversion (one launch for x, wug-perm, wd) --
// float4-unit ranges: x [0, 7340032), wug [7340032, 14680064), wd [.., 18350080)
// wug permute (64-row groups): out row r: g = r>>6, w = r&63;
//   src = g*32 + (w&31) + (w>=32 ? 2048 : 0)
// -> each 64-row group = 32 gate rows + 32 up rows of the same 32-wide e-block,
// so the two 32-col n-frags of a wave pair gate/up IN-LANE (col = lane&31).
__global__ __launch_bounds__(256) void cvt_all(const float* __restrict__ x,
                                               const float* __restrict__ wug,
                                               const float* __restrict__ wd,
                                               unsigned short* __restrict__ xb,
                                               unsigned short* __restrict__ wub,
                                               unsigned short* __restrict__ wdb) {
  int i = blockIdx.x * blockDim.x + threadIdx.x;
  const int stride = gridDim.x * blockDim.x;
  for (; i < 18350080; i += stride) {
    float4 v; ushort4* dp;
    if (i < 7340032) {
      v = ((const float4*)x)[i];
      dp = (ushort4*)xb + i;
    } else if (i < 14680064) {
      const int k = i - 7340032;
      const int r = k / 1792, c = k - r * 1792;
      const int g = r >> 6, w = r & 63;
      const int src = g * 32 + (w & 31) + ((w & 32) ? 2048 : 0);
      v = ((const float4*)wug)[(size_t)src * 1792 + c];
      dp = (ushort4*)wub + k;
    } else {
      const int k = i - 14680064;
      v = ((const float4*)wd)[k];
      dp = (ushort4*)wdb + k;
    }
    ushort4 o;
    o.x = f2bf(v.x); o.y = f2bf(v.y); o.z = f2bf(v.z); o.w = f2bf(v.w);
    *dp = o;
  }
}

// ---------- 256x256 NT bf16 GEMM: round-9 skeleton + mfma_32x32x16 ----------
// C[m,n] = sum_k A[m,k]*B[n,k].  512 thr = 8 waves (2Mx4N), wave-tile 128x64.
// MFMA 32x32x16 (2382 TF ceiling vs 2075 for 16x16x32; 4x fewer instructions,
// identical LDS fragment traffic). acc = 4mt x 2nt f32x16 = 128 regs.
// LDS: 2 buffers x (A 32K | B 32K) = 128 KiB. Per K-tile (BK=64), per wave:
//   top  (G_first resident): read A mt0-1 (8 b128) + B all (8); stage
//         G_first(t+1)=6; MFMA 16 (mt0-1 x nt0-1 x kst0-3); vmcnt(6)
//         [drains G_late(t), ~1 half-tile old]; barrier
//   bot  (G_late resident):  read A mt2-3 (8); stage G_late(t+1)=2;
//         MFMA 16; vmcnt(2) [drains G_first(t+1)]; barrier
// G_first = {A rows 0-63,128-191 (= mt0-1 for both wr), B all}; G_late =
// {A rows 64-127,192-255}. Counted vmcnt only, never 0 (except final tile).
// No inline lgkm asm — compiler emits fine-grained lgkmcnt for ds_read->MFMA.
// Swizzle: row r = 128B line; 16B phys slot p holds logical q = p ^ (r&7);
// staging pre-swizzles the per-lane GLOBAL source, LDS dest linear (m173).
// 32x32 frag read: lane l -> row l&31 (+32*mt), slot q = kst*2 + (l>>5);
// same aliasing structure as the verified 0-conflict 16x16 pattern.
// C/D layout (m74/m101): col = lane&31, row = (reg&3) + 8*(reg>>2) + 4*(l>>5).
// FUSE_SWIGLU: B pre-permuted (64-row groups) -> nt0 = gate, nt1 = up of the
// same e-cols in-lane; h = silu(g)*u, write [M, N/2] bf16.
template <int K, int N, bool FUSE_SWIGLU>
__global__ __launch_bounds__(512, 1) void gemm_nt(const unsigned short* __restrict__ A,
                                                  const unsigned short* __restrict__ B,
                                                  void* __restrict__ Cv) {
  extern __shared__ char sm[];   // 131072 B: buf{0,1} x [A 32K | B 32K]
  constexpr int nbx = N / 256;
  constexpr int nwg = (4096 / 256) * nbx;
  constexpr size_t K2 = (size_t)K * 2;
  constexpr int nt = K / 64;     // K-tiles

  // T1: bijective XCD swizzle (nwg % 8 == 0 for both GEMMs)
  const int bid = blockIdx.x;
  constexpr int q8 = nwg / 8;
  const int swz = (bid & 7) * q8 + (bid >> 3);
  const int bx = swz % nbx, by = swz / nbx;
  const int row0 = by * 256, col0 = bx * 256;

  const int tid = threadIdx.x, wave = tid >> 6, lane = tid & 63;
  const int wr = wave >> 2, wc = wave & 3;       // wave 2x4 grid
  const int l31 = lane & 31, hi = lane >> 5;

  // ---- staging setup: per thread 1 load per 8KB quarter (64 rows x 128B) ----
  const int l3 = lane >> 3, p7 = lane & 7;
  const int qgl = p7 ^ l3;                  // pre-swizzled logical 16B slot
  const char* srcA = (const char*)A + (size_t)(row0 + wave * 8 + l3) * K2 + qgl * 16;
  const char* srcB = (const char*)B + (size_t)(col0 + wave * 8 + l3) * K2 + qgl * 16;
  const int dstq = wave * 1024 + lane * 16; // linear dest within a quarter

#define STAGE_AQ(qa, tt, bufo) \
  async_cp16(srcA + (size_t)(qa) * 64 * K2 + (size_t)(tt) * 128, \
             sm + (bufo) + (qa) * 8192 + dstq)
#define STAGE_BQ(qb, tt, bufo) \
  async_cp16(srcB + (size_t)(qb) * 64 * K2 + (size_t)(tt) * 128, \
             sm + (bufo) + 32768 + (qb) * 8192 + dstq)

  // ---- fragment read offsets: row r byte = r*128 + ((kst*2+hi)^(r&7))*16 ----
  const int r7 = l31 & 7;
  int sA[4], sB[4];                          // per-kst swizzled slot bytes
#pragma unroll
  for (int kst = 0; kst < 4; ++kst) {
    sA[kst] = (((kst << 1) | hi) ^ r7) << 4;
    sB[kst] = sA[kst];
  }
  const int offAb = wr * 128 * 128 + l31 * 128;          // + mt*32*128 + sA[kst]
  const int offBb = 32768 + wc * 64 * 128 + l31 * 128;   // + nt*32*128 + sB[kst]

  f32x16 acc[4][2];
#pragma unroll
  for (int m = 0; m < 4; ++m)
#pragma unroll
    for (int n = 0; n < 2; ++n)
#pragma unroll
      for (int j = 0; j < 16; ++j) acc[m][n][j] = 0.f;

  // prologue: stage tile 0 (G_first 6, then G_late 2); drain G_first; sync
  STAGE_AQ(0, 0, 0); STAGE_AQ(2, 0, 0);
  STAGE_BQ(0, 0, 0); STAGE_BQ(1, 0, 0); STAGE_BQ(2, 0, 0); STAGE_BQ(3, 0, 0);
  STAGE_AQ(1, 0, 0); STAGE_AQ(3, 0, 0);
  asm volatile("s_waitcnt vmcnt(2)" ::: "memory");
  __builtin_amdgcn_s_barrier();

  // invariant at tile-t top: G_first(t) resident; own outstanding = G_late(t)=2
  for (int t = 0; t < nt; ++t) {
    const char* cur = sm + (t & 1) * 65536;
    const int nxo = ((t + 1) & 1) * 65536;
    const bool more = (t + 1 < nt);

    // ======== top half: mt0-1 x nt0-1, all 4 ksts ========
    bf16x8 a0[2][4], b[2][4];
#pragma unroll
    for (int mt = 0; mt < 2; ++mt)
#pragma unroll
      for (int kst = 0; kst < 4; ++kst)
        a0[mt][kst] = *(const bf16x8*)(cur + offAb + mt * 4096 + sA[kst]);
#pragma unroll
    for (int n = 0; n < 2; ++n)
#pragma unroll
      for (int kst = 0; kst < 4; ++kst)
        b[n][kst] = *(const bf16x8*)(cur + offBb + n * 4096 + sB[kst]);
    if (more) {   // stage G_first(t+1): A quads 0,2 + all B (6 loads)
      STAGE_AQ(0, t + 1, nxo); STAGE_AQ(2, t + 1, nxo);
      STAGE_BQ(0, t + 1, nxo); STAGE_BQ(1, t + 1, nxo);
      STAGE_BQ(2, t + 1, nxo); STAGE_BQ(3, t + 1, nxo);
    }
    __builtin_amdgcn_s_setprio(1);
#pragma unroll
    for (int kst = 0; kst < 4; ++kst)
#pragma unroll
      for (int mt = 0; mt < 2; ++mt)
#pragma unroll
        for (int n = 0; n < 2; ++n)
          acc[mt][n] = __builtin_amdgcn_mfma_f32_32x32x16_bf16(a0[mt][kst], b[n][kst], acc[mt][n], 0, 0, 0);
    __builtin_amdgcn_s_setprio(0);
    if (more) { asm volatile("s_waitcnt vmcnt(6)" ::: "memory"); }  // G_late(t) resident
    else      { asm volatile("s_waitcnt vmcnt(0)" ::: "memory"); }
    __builtin_amdgcn_s_barrier();

    // ======== bottom half: mt2-3 x nt0-1 (B frags live in regs) ========
    bf16x8 a1[2][4];
#pragma unroll
    for (int mt = 0; mt < 2; ++mt)
#pragma unroll
      for (int kst = 0; kst < 4; ++kst)
        a1[mt][kst] = *(const bf16x8*)(cur + offAb + (mt + 2) * 4096 + sA[kst]);
    if (more) { STAGE_AQ(1, t + 1, nxo); STAGE_AQ(3, t + 1, nxo); }  // G_late(t+1)
    __builtin_amdgcn_s_setprio(1);
#pragma unroll
    for (int kst = 0; kst < 4; ++kst)
#pragma unroll
      for (int mt = 0; mt < 2; ++mt)
#pragma unroll
        for (int n = 0; n < 2; ++n)
          acc[mt + 2][n] = __builtin_amdgcn_mfma_f32_32x32x16_bf16(a1[mt][kst], b[n][kst], acc[mt + 2][n], 0, 0, 0);
    __builtin_amdgcn_s_setprio(0);
    if (more) {
      asm volatile("s_waitcnt vmcnt(2)" ::: "memory");  // G_first(t+1) resident
      __builtin_amdgcn_s_barrier();
    }
  }
#undef STAGE_AQ
#undef STAGE_BQ

  // ---- epilogue: C/D col = lane&31, row = (j&3) + 8*(j>>2) + 4*hi ----
  const int rowb = row0 + wr * 128;
  if (FUSE_SWIGLU) {
    // nt0 = gate, nt1 = up, same e-cols in-lane (64-row pre-permuted B)
    unsigned short* Hp = (unsigned short*)Cv;
    const int ecb = ((col0 + wc * 64) >> 1) + l31;
#pragma unroll
    for (int mt = 0; mt < 4; ++mt)
#pragma unroll
      for (int j = 0; j < 16; ++j) {
        const int row = rowb + mt * 32 + (j & 3) + 8 * (j >> 2) + 4 * hi;
        const float gv = acc[mt][0][j];
        const float uv = acc[mt][1][j];
        const float s  = gv / (1.0f + __expf(-gv));
        Hp[(size_t)row * (N / 2) + ecb] = f2bf(s * uv);
      }
  } else {
    float* Cp = (float*)Cv;
    const int colb = col0 + wc * 64 + l31;
#pragma unroll
    for (int mt = 0; mt < 4; ++mt)
#pragma unroll
      for (int n = 0; n < 2; ++n)
#pragma unroll
        for (int j = 0; j < 16; ++j) {
          const int row = rowb + mt * 32 + (j & 3) + 8 * (j >> 2) + 4 * hi;
          Cp[(size_t)row * N + (colb + n * 32)] = acc[mt][n][j];
        }
  }
}

// ---------- launch ----------
extern "C" void kernel_launch(void* const* d_in, const int* in_sizes, int n_in,
                              void* d_out, int out_size, void* d_ws, size_t ws_size,
                              hipStream_t stream) {
  const int M = 4096, K = 7168, E = 2048;

  const float* x   = (const float*)d_in[0];  // [M,K]
  const float* wug = (const float*)d_in[1];  // [2E,K]
  const float* wd  = (const float*)d_in[2];  // [K,E]
  float* out = (float*)d_out;                // [M,K]

  // workspace layout (bytes)
  char* ws = (char*)d_ws;
  unsigned short* xb  = (unsigned short*)(ws);               //  58,720,256
  unsigned short* wub = (unsigned short*)(ws + 58720256);    //  58,720,256 (permuted)
  unsigned short* wdb = (unsigned short*)(ws + 117440512);   //  29,360,128
  unsigned short* h   = (unsigned short*)(ws + 146800640);   //  16,777,216
  if (ws_size < 163577856) return;                           // need ~156 MiB

  // allow 128 KiB dynamic LDS (host-side calls, safe under graph capture)
  hipFuncSetAttribute((const void*)gemm_nt<7168, 4096, true>,
                      hipFuncAttributeMaxDynamicSharedMemorySize, 131072);
  hipFuncSetAttribute((const void*)gemm_nt<2048, 7168, false>,
                      hipFuncAttributeMaxDynamicSharedMemorySize, 131072);

  // 1) cast inputs to bf16 (single merged launch; wug 64-row gate/up permute)
  cvt_all<<<2048, 256, 0, stream>>>(x, wug, wd, xb, wub, wdb);

  // 2) h = swiglu(x @ w_up_gate^T) fused   [4096, 2048] bf16  (16x16 = 256 blocks)
  gemm_nt<7168, 4096, true><<<256, 512, 131072, stream>>>(xb, wub, h);

  // 3) out = h @ w_down^T     [4096, 7168] fp32  (16x28 = 448 blocks)
  gemm_nt<2048, 7168, false><<<448, 512, 131072, stream>>>(h, wdb, out);
}